// Round 7
// baseline (139.557 us; speedup 1.0000x reference)
//
#include <hip/hip_runtime.h>
#include <cfloat>

typedef __attribute__((ext_vector_type(8))) short short8;
typedef __attribute__((ext_vector_type(4))) float f32x4;

// Shapes: z_e [32,64,64,64] fp32, codebook [512,64] fp32.
// d_out (fp32 flat): z_q_st [8388608] ++ indices [131072] ++ loss [1].
constexpr int C_DIM    = 64;
constexpr int K_CODES  = 512;
constexpr int HW       = 4096;
constexpr int CHW      = 262144;
constexpr int NPTS     = 131072;
constexpr int ZQ_SIZE  = 8388608;
constexpr int IDX_OFF  = ZQ_SIZE;
constexpr int LOSS_OFF = ZQ_SIZE + NPTS;
constexpr int TILE     = 256;      // points per block
constexpr int THREADS  = 512;      // 8 waves
constexpr int NSLOT    = 16;       // candidate slots per point
constexpr int NCHUNK   = 4096;     // 16B chunks of bf16 codebook (64 KB)
constexpr size_t WS_BF16 = (size_t)K_CODES * C_DIM * 2;   // 65536 B
constexpr size_t WS_NEED = WS_BF16 + (size_t)K_CODES * 4; // + Bs

__device__ __forceinline__ unsigned short f32_to_bf16_rne(float f) {
    unsigned u = __float_as_uint(f);
    unsigned r = u + 0x7fffu + ((u >> 16) & 1u);
    return (unsigned short)(r >> 16);
}

// numpy pairwise_sum of 64 fp32 squares (8-accumulator scheme) — bit-exact
// vs np.sum(a*a, axis=1).
template <int STRIDE>
__device__ __forceinline__ float np_sumsq64(const float* __restrict__ a) {
    float r[8];
#pragma unroll
    for (int j = 0; j < 8; ++j) { const float v = a[j * STRIDE]; r[j] = __fmul_rn(v, v); }
#pragma unroll
    for (int i = 8; i < 64; i += 8)
#pragma unroll
        for (int j = 0; j < 8; ++j) {
            const float v = a[(i + j) * STRIDE];
            r[j] = __fadd_rn(r[j], __fmul_rn(v, v));
        }
    return __fadd_rn(
        __fadd_rn(__fadd_rn(r[0], r[1]), __fadd_rn(r[2], r[3])),
        __fadd_rn(__fadd_rn(r[4], r[5]), __fadd_rn(r[6], r[7])));
}

__global__ void vq_zero(float* __restrict__ out) { out[LOSS_OFF] = 0.0f; }

// Prep: bf16 codebook into ws in MFMA B-fragment tile order:
//   chunk(t,h,q,cl) -> 8 bf16 of code k=t*16+cl, channels h*32+q*8+..7,
//   at linear 16B-chunk index ((t*2+h)*4+q)*16 + cl.
// Also Bs (numpy pairwise) and loss zeroing.
__global__ void vq_prep(const float* __restrict__ cb, unsigned short* __restrict__ wsb,
                        float* __restrict__ wsB, float* __restrict__ out) {
    const int gid = blockIdx.x * 256 + threadIdx.x;  // 0..32767
    const int j = gid & 7, i = gid >> 3;             // chunk i, elem j
    const int cl = i & 15, q = (i >> 4) & 3, h = (i >> 6) & 1, t = i >> 7;
    const int k = t * 16 + cl, c = h * 32 + q * 8 + j;
    wsb[gid] = f32_to_bf16_rne(cb[k * C_DIM + c]);
    if (gid < K_CODES) wsB[gid] = np_sumsq64<1>(cb + gid * C_DIM);
    if (gid == 0) out[LOSS_OFF] = 0.0f;
}

__global__ __launch_bounds__(THREADS, 4) void vq_idx(const float* __restrict__ ze,
                                                     const float* __restrict__ cb,
                                                     float* __restrict__ out,
                                                     const unsigned short* __restrict__ wsb,
                                                     const float* __restrict__ wsB,
                                                     int use_ws)
{
    __shared__ uint4  eh4[NCHUNK];          // 64 KB: whole bf16 codebook, tiled
    __shared__ float  BsL[K_CODES];
    __shared__ float  As[TILE];
    __shared__ unsigned short cand[TILE * NSLOT];
    __shared__ int    cnt[TILE];
    __shared__ int    bestk[TILE];
    __shared__ double lred[8];

    const int tid  = threadIdx.x;           // 0..511 (8 waves)
    const int lane = tid & 63, w = tid >> 6;
    const int quad = lane >> 4, l15 = lane & 15;
    const int n0   = blockIdx.x * TILE;     // grid = 512 (exactly 2 blocks/CU)
    const int b    = n0 >> 12, hw0 = n0 & (HW - 1);
    const float* zebase = ze + b * CHW + hw0;

    // ---- init: Bs, As, cnt, and the single 64 KB codebook staging ----
    if (use_ws) {
        BsL[tid] = wsB[tid];
        const uint4* src = (const uint4*)wsb;
#pragma unroll
        for (int i = 0; i < 8; ++i) eh4[tid + THREADS * i] = src[tid + THREADS * i];
    } else {
        for (int k = tid; k < K_CODES; k += THREADS) BsL[k] = np_sumsq64<1>(cb + k * C_DIM);
#pragma unroll
        for (int it = 0; it < 8; ++it) {
            const int i = tid + THREADS * it;
            const int cl = i & 15, q = (i >> 4) & 3, h = (i >> 6) & 1, t = i >> 7;
            const float* src = cb + (t * 16 + cl) * C_DIM + h * 32 + q * 8;
            const float4 f0 = *(const float4*)src, f1 = *(const float4*)(src + 4);
            uint4 o;
            o.x = (unsigned)f32_to_bf16_rne(f0.x) | ((unsigned)f32_to_bf16_rne(f0.y) << 16);
            o.y = (unsigned)f32_to_bf16_rne(f0.z) | ((unsigned)f32_to_bf16_rne(f0.w) << 16);
            o.z = (unsigned)f32_to_bf16_rne(f1.x) | ((unsigned)f32_to_bf16_rne(f1.y) << 16);
            o.w = (unsigned)f32_to_bf16_rne(f1.z) | ((unsigned)f32_to_bf16_rne(f1.w) << 16);
            eh4[i] = o;
        }
    }
    if (tid < TILE) { As[tid] = np_sumsq64<HW>(zebase + tid); cnt[tid] = 0; }
    __syncthreads();

    // ---- A fragments (bf16 RNE of x): A[m=lane&15][k=quad*8+j]; wave w owns
    // points w*32 .. w*32+31 (rt in {0,1}) ----
    short8 afr[2][2];
    float  A_pt[2][4], thr[2][4], runmin[2][4];
#pragma unroll
    for (int rt = 0; rt < 2; ++rt) {
        const int pt = w * 32 + rt * 16 + l15;
#pragma unroll
        for (int kc = 0; kc < 2; ++kc) {
            union { unsigned short s[8]; short8 v; } u;
#pragma unroll
            for (int j = 0; j < 8; ++j) {
                const int c = kc * 32 + quad * 8 + j;
                u.s[j] = f32_to_bf16_rne(zebase[c * HW + pt]);
            }
            afr[rt][kc] = u.v;
        }
#pragma unroll
        for (int r = 0; r < 4; ++r) {
            A_pt[rt][r]   = As[w * 32 + rt * 16 + quad * 4 + r];
            runmin[rt][r] = FLT_MAX;
        }
    }

    // ---- pass 1: approx-min over all 512 codes; no barriers, no re-staging.
    // b-frag read = wave-contiguous 1024 B (conflict-free ds_read_b128).
    for (int t = 0; t < 32; ++t) {
        const short8 b0 = *(const short8*)&eh4[(t * 8 + quad) * 16 + l15];
        const short8 b1 = *(const short8*)&eh4[(t * 8 + 4 + quad) * 16 + l15];
        const float  bs = BsL[t * 16 + l15];
#pragma unroll
        for (int rt = 0; rt < 2; ++rt) {
            f32x4 acc = {0.f, 0.f, 0.f, 0.f};
            acc = __builtin_amdgcn_mfma_f32_16x16x32_bf16(afr[rt][0], b0, acc, 0, 0, 0);
            acc = __builtin_amdgcn_mfma_f32_16x16x32_bf16(afr[rt][1], b1, acc, 0, 0, 0);
#pragma unroll
            for (int r = 0; r < 4; ++r) {
                const float D = fmaf(-2.f, acc[r], __fadd_rn(A_pt[rt][r], bs));
                runmin[rt][r] = fminf(runmin[rt][r], D);
            }
        }
    }
    // cross-lane min over the 16 l15-lanes sharing each point; margin 3x the
    // rigorous bf16-vs-chain error bound.
#pragma unroll
    for (int rt = 0; rt < 2; ++rt)
#pragma unroll
        for (int r = 0; r < 4; ++r) {
            float v = runmin[rt][r];
#pragma unroll
            for (int m = 1; m < 16; m <<= 1) v = fminf(v, __shfl_xor(v, m, 64));
            thr[rt][r] = v + (4e-4f * sqrtf(A_pt[rt][r]) + 3e-4f);
        }

    // ---- pass 2: recompute identical D, collect candidates ----
    for (int t = 0; t < 32; ++t) {
        const short8 b0 = *(const short8*)&eh4[(t * 8 + quad) * 16 + l15];
        const short8 b1 = *(const short8*)&eh4[(t * 8 + 4 + quad) * 16 + l15];
        const float  bs = BsL[t * 16 + l15];
#pragma unroll
        for (int rt = 0; rt < 2; ++rt) {
            f32x4 acc = {0.f, 0.f, 0.f, 0.f};
            acc = __builtin_amdgcn_mfma_f32_16x16x32_bf16(afr[rt][0], b0, acc, 0, 0, 0);
            acc = __builtin_amdgcn_mfma_f32_16x16x32_bf16(afr[rt][1], b1, acc, 0, 0, 0);
#pragma unroll
            for (int r = 0; r < 4; ++r) {
                const float D = fmaf(-2.f, acc[r], __fadd_rn(A_pt[rt][r], bs));
                if (D <= thr[rt][r]) {
                    const int pt = w * 32 + rt * 16 + quad * 4 + r;
                    const int p = atomicAdd(&cnt[pt], 1);
                    if (p < NSLOT) cand[pt * NSLOT + p] = (unsigned short)(t * 16 + l15);
                }
            }
        }
    }
    __syncthreads();

    // ---- exact rescore (bit-exact numpy/BLAS chain), one thread per point ----
    if (tid < TILE) {
        const float Av = As[tid];
        const int c = cnt[tid];
        float bD = FLT_MAX; int bK = K_CODES;
        if (c <= NSLOT) {
            for (int i = 0; i < c; ++i) {
                const int k = cand[tid * NSLOT + i];
                const float* er = cb + k * C_DIM;
                float M = 0.f;
#pragma unroll
                for (int cc = 0; cc < 64; ++cc) M = fmaf(zebase[cc * HW + tid], er[cc], M);
                const float D = fmaf(-2.f, M, __fadd_rn(Av, BsL[k]));
                if (D < bD || (D == bD && k < bK)) { bD = D; bK = k; }
            }
        } else {  // overflow: exact full scan (ascending, strict <)
            for (int k = 0; k < K_CODES; ++k) {
                const float* er = cb + k * C_DIM;
                float M = 0.f;
#pragma unroll
                for (int cc = 0; cc < 64; ++cc) M = fmaf(zebase[cc * HW + tid], er[cc], M);
                const float D = fmaf(-2.f, M, __fadd_rn(Av, BsL[k]));
                if (D < bD) { bD = D; bK = k; }
            }
        }
        bestk[tid] = bK;
        out[IDX_OFF + n0 + tid] = (float)bK;
    }
    __syncthreads();

    // ---- epilogue: z_q_st (ref formula bitwise) + loss, float4 along hw ----
    double ls = 0.0;
#pragma unroll
    for (int it = 0; it < 8; ++it) {
        const int task = tid + THREADS * it;     // 4096 tasks = 64 c x 64 quads
        const int c = task >> 6, q = task & 63;
        const float4 xz = *(const float4*)(zebase + c * HW + 4 * q);
        float o[4];
#pragma unroll
        for (int j = 0; j < 4; ++j) {
            const int k = bestk[4 * q + j];
            const float ev = cb[k * C_DIM + c];  // gather, L1/L2-hot
            const float xv = (j == 0) ? xz.x : (j == 1) ? xz.y : (j == 2) ? xz.z : xz.w;
            const float d = __fsub_rn(ev, xv);   // ref: z_q - z_e
            o[j] = __fadd_rn(xv, d);             // ref: z_e + (...)
            ls = fma((double)d, (double)d, ls);
        }
        *(float4*)(out + b * CHW + c * HW + hw0 + 4 * q) = make_float4(o[0], o[1], o[2], o[3]);
    }
#pragma unroll
    for (int off = 32; off > 0; off >>= 1) ls += __shfl_xor(ls, off, 64);
    if ((tid & 63) == 0) lred[w] = ls;
    __syncthreads();
    if (tid == 0) {
        double t = 0.0;
#pragma unroll
        for (int i = 0; i < 8; ++i) t += lred[i];
        atomicAdd(out + LOSS_OFF, (float)(t * (1.25 / (double)ZQ_SIZE)));
    }
}

extern "C" void kernel_launch(void* const* d_in, const int* in_sizes, int n_in,
                              void* d_out, int out_size, void* d_ws, size_t ws_size,
                              hipStream_t stream) {
    (void)in_sizes; (void)n_in; (void)out_size;
    const float* ze = (const float*)d_in[0];
    const float* cb = (const float*)d_in[1];
    float* out = (float*)d_out;
    const int use_ws = (ws_size >= WS_NEED) ? 1 : 0;
    unsigned short* wsb = (unsigned short*)d_ws;
    float* wsB = (float*)((char*)d_ws + WS_BF16);

    if (use_ws) vq_prep<<<(K_CODES * C_DIM) / 256, 256, 0, stream>>>(cb, wsb, wsB, out);
    else        vq_zero<<<1, 1, 0, stream>>>(out);
    vq_idx<<<NPTS / TILE, THREADS, 0, stream>>>(ze, cb, out, wsb, wsB, use_ws);
}